// Round 2
// baseline (1240.977 us; speedup 1.0000x reference)
//
#include <hip/hip_runtime.h>
#include <cmath>

constexpr int kLevels = 16;
constexpr unsigned kLog2T = 19;
constexpr unsigned kT = 1u << kLog2T;
constexpr unsigned kMask = kT - 1u;
constexpr unsigned P1 = 2654435761u;
constexpr unsigned P2 = 805459861u;

struct LevelParams {
  float scale[kLevels];   // res * 0.5  (u = (x+1) * res/2)
  float resm1[kLevels];   // res - 1    (clip bound for floor(u))
};

// Persistent, generation-aligned grid:
//  - grid = 1024 blocks, __launch_bounds__(256,4) => >=4 blocks/CU resident,
//    so ALL blocks are resident from t=0. Each thread handles exactly 4
//    points (stride = 262144), so all waves sweep levels 0..15 in phase:
//    the concurrent table working set stays ~1 level (4 MB) ~= per-XCD L2,
//    instead of all 16 tables (64 MB) as with the non-persistent launch.
//  - full #pragma unroll over levels: 128 independent gathers per point,
//    static indexing of the 32-float accumulator (runtime-indexed register
//    arrays would spill to scratch).
//  - output accumulated in registers, written once as 8x float4 per row:
//    full-line writes while hot in L2 -> no partial-line RMW.
__global__ __launch_bounds__(256, 4) void hash_embed_kernel(
    const float* __restrict__ x,
    const float* __restrict__ tables,
    float* __restrict__ out,
    LevelParams lp, int B)
{
  const int t0 = blockIdx.x * 256 + threadIdx.x;
  const int stride = gridDim.x * 256;
  const float2* __restrict__ tblbase = (const float2*)tables;

  for (int p = t0; p < B; p += stride) {
    const float px = x[3 * p + 0];
    const float py = x[3 * p + 1];
    const float pz = x[3 * p + 2];

    float acc[2 * kLevels];

#pragma unroll
    for (int l = 0; l < kLevels; ++l) {
      const float s   = lp.scale[l];
      const float rm1 = lp.resm1[l];
      const float2* __restrict__ tbl = tblbase + (size_t)l * kT;

      const float ux = (px + 1.0f) * s;
      const float uy = (py + 1.0f) * s;
      const float uz = (pz + 1.0f) * s;

      const float fx = fminf(fmaxf(floorf(ux), 0.0f), rm1);
      const float fy = fminf(fmaxf(floorf(uy), 0.0f), rm1);
      const float fz = fminf(fmaxf(floorf(uz), 0.0f), rm1);

      const float tx = ux - fx;
      const float ty = uy - fy;
      const float tz = uz - fz;

      const unsigned ix = (unsigned)fx;
      const unsigned iy = (unsigned)fy;
      const unsigned iz = (unsigned)fz;

      // h = (ix+ox) ^ (iy+oy)*P1 ^ (iz+oz)*P2 (uint32 wraparound), 2 mults.
      const unsigned ax0 = ix;
      const unsigned ax1 = ix + 1u;
      const unsigned by0 = iy * P1;
      const unsigned by1 = by0 + P1;
      const unsigned cz0 = iz * P2;
      const unsigned cz1 = cz0 + P2;

      const unsigned bc00 = by0 ^ cz0;
      const unsigned bc10 = by1 ^ cz0;
      const unsigned bc01 = by0 ^ cz1;
      const unsigned bc11 = by1 ^ cz1;

      const float2 e000 = tbl[(ax0 ^ bc00) & kMask];
      const float2 e100 = tbl[(ax1 ^ bc00) & kMask];
      const float2 e010 = tbl[(ax0 ^ bc10) & kMask];
      const float2 e110 = tbl[(ax1 ^ bc10) & kMask];
      const float2 e001 = tbl[(ax0 ^ bc01) & kMask];
      const float2 e101 = tbl[(ax1 ^ bc01) & kMask];
      const float2 e011 = tbl[(ax0 ^ bc11) & kMask];
      const float2 e111 = tbl[(ax1 ^ bc11) & kMask];

      const float wx1 = tx, wx0 = 1.0f - tx;
      const float wy1 = ty, wy0 = 1.0f - ty;
      const float wz1 = tz, wz0 = 1.0f - tz;

      const float wyz00 = wy0 * wz0;
      const float wyz10 = wy1 * wz0;
      const float wyz01 = wy0 * wz1;
      const float wyz11 = wy1 * wz1;

      const float w000 = wx0 * wyz00, w100 = wx1 * wyz00;
      const float w010 = wx0 * wyz10, w110 = wx1 * wyz10;
      const float w001 = wx0 * wyz01, w101 = wx1 * wyz01;
      const float w011 = wx0 * wyz11, w111 = wx1 * wyz11;

      float f0 = w000 * e000.x;
      float f1 = w000 * e000.y;
      f0 = fmaf(w100, e100.x, f0);  f1 = fmaf(w100, e100.y, f1);
      f0 = fmaf(w010, e010.x, f0);  f1 = fmaf(w010, e010.y, f1);
      f0 = fmaf(w110, e110.x, f0);  f1 = fmaf(w110, e110.y, f1);
      f0 = fmaf(w001, e001.x, f0);  f1 = fmaf(w001, e001.y, f1);
      f0 = fmaf(w101, e101.x, f0);  f1 = fmaf(w101, e101.y, f1);
      f0 = fmaf(w011, e011.x, f0);  f1 = fmaf(w011, e011.y, f1);
      f0 = fmaf(w111, e111.x, f0);  f1 = fmaf(w111, e111.y, f1);

      acc[2 * l + 0] = f0;
      acc[2 * l + 1] = f1;
    }

    // One full 128B row per thread, written once, vectorized.
    float4* __restrict__ orow = (float4*)(out + (size_t)p * (2 * kLevels));
#pragma unroll
    for (int q = 0; q < 8; ++q) {
      orow[q] = make_float4(acc[4 * q + 0], acc[4 * q + 1],
                            acc[4 * q + 2], acc[4 * q + 3]);
    }
  }
}

extern "C" void kernel_launch(void* const* d_in, const int* in_sizes, int n_in,
                              void* d_out, int out_size, void* d_ws, size_t ws_size,
                              hipStream_t stream) {
  const float* x      = (const float*)d_in[0];
  const float* tables = (const float*)d_in[1];
  float* out          = (float*)d_out;
  const int B = in_sizes[0] / 3;

  // Replicate numpy's double-precision resolution computation bit-exactly.
  LevelParams lp;
  const double factor = exp((log(512.0) - log(16.0)) / 15.0);
  for (int i = 0; i < kLevels; ++i) {
    const int res = (int)floor(16.0 * pow(factor, (double)i));
    lp.scale[i] = (float)res * 0.5f;
    lp.resm1[i] = (float)(res - 1);
  }

  const int block = 256;
  const int grid = 1024;   // persistent: all blocks resident at >=4 blocks/CU
  hipLaunchKernelGGL(hash_embed_kernel, dim3(grid), dim3(block), 0, stream,
                     x, tables, out, lp, B);
}

// Round 3
// 761.889 us; speedup vs baseline: 1.6288x; 1.6288x over previous
//
#include <hip/hip_runtime.h>
#include <cmath>

constexpr int kLevels = 16;
constexpr unsigned kLog2T = 19;
constexpr unsigned kT = 1u << kLog2T;
constexpr unsigned kMask = kT - 1u;
constexpr unsigned P1 = 2654435761u;
constexpr unsigned P2 = 805459861u;

struct LevelParams {
  float scale[kLevels];   // res * 0.5  (u = (x+1) * res/2)
  float resm1[kLevels];   // res - 1    (clip bound for floor(u))
};

// ---------------------------------------------------------------------------
// Per-level-range kernel. Writes TRANSPOSED scratch out_t[l][p][2] so that a
// single level's store is full-line coalesced (512 B per wave-instr), instead
// of 8 B per 128 B output row. Chip-wide level phase is enforced by launching
// one dispatch per fine level: the 4 MB table of the active level fits each
// XCD's 4 MB L2, so gathers become L2 hits instead of fabric misses.
// ---------------------------------------------------------------------------
template <int LO, int HI>
__global__ __launch_bounds__(256) void level_kernel(
    const float* __restrict__ x,
    const float* __restrict__ tables,
    float* __restrict__ out_t,   // [kLevels][B][2]
    LevelParams lp, int B)
{
  const int p = blockIdx.x * 256 + threadIdx.x;
  if (p >= B) return;

  const float px = x[3 * p + 0];
  const float py = x[3 * p + 1];
  const float pz = x[3 * p + 2];

#pragma unroll
  for (int l = LO; l < HI; ++l) {
    const float s   = lp.scale[l];
    const float rm1 = lp.resm1[l];
    const float2* __restrict__ tbl = (const float2*)tables + (size_t)l * kT;

    const float ux = (px + 1.0f) * s;
    const float uy = (py + 1.0f) * s;
    const float uz = (pz + 1.0f) * s;

    const float fx = fminf(fmaxf(floorf(ux), 0.0f), rm1);
    const float fy = fminf(fmaxf(floorf(uy), 0.0f), rm1);
    const float fz = fminf(fmaxf(floorf(uz), 0.0f), rm1);

    const float tx = ux - fx;
    const float ty = uy - fy;
    const float tz = uz - fz;

    const unsigned ix = (unsigned)fx;
    const unsigned iy = (unsigned)fy;
    const unsigned iz = (unsigned)fz;

    // h = (ix+ox) ^ (iy+oy)*P1 ^ (iz+oz)*P2 (uint32 wraparound), 2 mults.
    const unsigned ax0 = ix;
    const unsigned ax1 = ix + 1u;
    const unsigned by0 = iy * P1;
    const unsigned by1 = by0 + P1;
    const unsigned cz0 = iz * P2;
    const unsigned cz1 = cz0 + P2;

    const unsigned bc00 = by0 ^ cz0;
    const unsigned bc10 = by1 ^ cz0;
    const unsigned bc01 = by0 ^ cz1;
    const unsigned bc11 = by1 ^ cz1;

    const float2 e000 = tbl[(ax0 ^ bc00) & kMask];
    const float2 e100 = tbl[(ax1 ^ bc00) & kMask];
    const float2 e010 = tbl[(ax0 ^ bc10) & kMask];
    const float2 e110 = tbl[(ax1 ^ bc10) & kMask];
    const float2 e001 = tbl[(ax0 ^ bc01) & kMask];
    const float2 e101 = tbl[(ax1 ^ bc01) & kMask];
    const float2 e011 = tbl[(ax0 ^ bc11) & kMask];
    const float2 e111 = tbl[(ax1 ^ bc11) & kMask];

    const float wx1 = tx, wx0 = 1.0f - tx;
    const float wy1 = ty, wy0 = 1.0f - ty;
    const float wz1 = tz, wz0 = 1.0f - tz;

    const float wyz00 = wy0 * wz0;
    const float wyz10 = wy1 * wz0;
    const float wyz01 = wy0 * wz1;
    const float wyz11 = wy1 * wz1;

    const float w000 = wx0 * wyz00, w100 = wx1 * wyz00;
    const float w010 = wx0 * wyz10, w110 = wx1 * wyz10;
    const float w001 = wx0 * wyz01, w101 = wx1 * wyz01;
    const float w011 = wx0 * wyz11, w111 = wx1 * wyz11;

    float f0 = w000 * e000.x;
    float f1 = w000 * e000.y;
    f0 = fmaf(w100, e100.x, f0);  f1 = fmaf(w100, e100.y, f1);
    f0 = fmaf(w010, e010.x, f0);  f1 = fmaf(w010, e010.y, f1);
    f0 = fmaf(w110, e110.x, f0);  f1 = fmaf(w110, e110.y, f1);
    f0 = fmaf(w001, e001.x, f0);  f1 = fmaf(w001, e001.y, f1);
    f0 = fmaf(w101, e101.x, f0);  f1 = fmaf(w101, e101.y, f1);
    f0 = fmaf(w011, e011.x, f0);  f1 = fmaf(w011, e011.y, f1);
    f0 = fmaf(w111, e111.x, f0);  f1 = fmaf(w111, e111.y, f1);

    // full-line coalesced 8B store into level-l slice
    ((float2*)(out_t + (size_t)l * 2 * B))[p] = make_float2(f0, f1);
  }
}

// ---------------------------------------------------------------------------
// Register transpose: lane = point. For each level l, the float2 load from
// out_t[l] is coalesced across lanes AND delivers exactly this lane's row
// element -> after 16 loads each lane holds its full 32-float row in regs;
// write it as 8x float4 (full-line).
// ---------------------------------------------------------------------------
__global__ __launch_bounds__(256) void transpose_kernel(
    const float* __restrict__ out_t, float* __restrict__ out, int B)
{
  const int p = blockIdx.x * 256 + threadIdx.x;
  if (p >= B) return;

  float r[2 * kLevels];
#pragma unroll
  for (int l = 0; l < kLevels; ++l) {
    const float2 v = ((const float2*)(out_t + (size_t)l * 2 * B))[p];
    r[2 * l + 0] = v.x;
    r[2 * l + 1] = v.y;
  }
  float4* __restrict__ orow = (float4*)(out + (size_t)p * (2 * kLevels));
#pragma unroll
  for (int q = 0; q < 8; ++q) {
    orow[q] = make_float4(r[4 * q + 0], r[4 * q + 1], r[4 * q + 2], r[4 * q + 3]);
  }
}

// ---------------------------------------------------------------------------
// Fallback monolith (round-1 kernel, known-correct, ~1.05 ms) used only if
// the workspace is too small for the transposed scratch.
// ---------------------------------------------------------------------------
__global__ __launch_bounds__(256) void monolith_kernel(
    const float* __restrict__ x,
    const float* __restrict__ tables,
    float* __restrict__ out,
    LevelParams lp, int B)
{
  const int b = blockIdx.x * 256 + threadIdx.x;
  if (b >= B) return;

  const float px = x[3 * b + 0];
  const float py = x[3 * b + 1];
  const float pz = x[3 * b + 2];
  float* orow = out + (size_t)b * (2 * kLevels);

  const float2* tbl = (const float2*)tables;
  for (int l = 0; l < kLevels; ++l, tbl += kT) {
    const float s   = lp.scale[l];
    const float rm1 = lp.resm1[l];

    const float ux = (px + 1.0f) * s;
    const float uy = (py + 1.0f) * s;
    const float uz = (pz + 1.0f) * s;

    const float fx = fminf(fmaxf(floorf(ux), 0.0f), rm1);
    const float fy = fminf(fmaxf(floorf(uy), 0.0f), rm1);
    const float fz = fminf(fmaxf(floorf(uz), 0.0f), rm1);

    const float tx = ux - fx;
    const float ty = uy - fy;
    const float tz = uz - fz;

    const unsigned ix = (unsigned)fx;
    const unsigned iy = (unsigned)fy;
    const unsigned iz = (unsigned)fz;

    const unsigned ax0 = ix, ax1 = ix + 1u;
    const unsigned by0 = iy * P1, by1 = by0 + P1;
    const unsigned cz0 = iz * P2, cz1 = cz0 + P2;

    const unsigned bc00 = by0 ^ cz0;
    const unsigned bc10 = by1 ^ cz0;
    const unsigned bc01 = by0 ^ cz1;
    const unsigned bc11 = by1 ^ cz1;

    const float2 e000 = tbl[(ax0 ^ bc00) & kMask];
    const float2 e100 = tbl[(ax1 ^ bc00) & kMask];
    const float2 e010 = tbl[(ax0 ^ bc10) & kMask];
    const float2 e110 = tbl[(ax1 ^ bc10) & kMask];
    const float2 e001 = tbl[(ax0 ^ bc01) & kMask];
    const float2 e101 = tbl[(ax1 ^ bc01) & kMask];
    const float2 e011 = tbl[(ax0 ^ bc11) & kMask];
    const float2 e111 = tbl[(ax1 ^ bc11) & kMask];

    const float wx1 = tx, wx0 = 1.0f - tx;
    const float wy1 = ty, wy0 = 1.0f - ty;
    const float wz1 = tz, wz0 = 1.0f - tz;

    const float wyz00 = wy0 * wz0;
    const float wyz10 = wy1 * wz0;
    const float wyz01 = wy0 * wz1;
    const float wyz11 = wy1 * wz1;

    const float w000 = wx0 * wyz00, w100 = wx1 * wyz00;
    const float w010 = wx0 * wyz10, w110 = wx1 * wyz10;
    const float w001 = wx0 * wyz01, w101 = wx1 * wyz01;
    const float w011 = wx0 * wyz11, w111 = wx1 * wyz11;

    float f0 = w000 * e000.x;
    float f1 = w000 * e000.y;
    f0 = fmaf(w100, e100.x, f0);  f1 = fmaf(w100, e100.y, f1);
    f0 = fmaf(w010, e010.x, f0);  f1 = fmaf(w010, e010.y, f1);
    f0 = fmaf(w110, e110.x, f0);  f1 = fmaf(w110, e110.y, f1);
    f0 = fmaf(w001, e001.x, f0);  f1 = fmaf(w001, e001.y, f1);
    f0 = fmaf(w101, e101.x, f0);  f1 = fmaf(w101, e101.y, f1);
    f0 = fmaf(w011, e011.x, f0);  f1 = fmaf(w011, e011.y, f1);
    f0 = fmaf(w111, e111.x, f0);  f1 = fmaf(w111, e111.y, f1);

    orow[2 * l + 0] = f0;
    orow[2 * l + 1] = f1;
  }
}

extern "C" void kernel_launch(void* const* d_in, const int* in_sizes, int n_in,
                              void* d_out, int out_size, void* d_ws, size_t ws_size,
                              hipStream_t stream) {
  const float* x      = (const float*)d_in[0];
  const float* tables = (const float*)d_in[1];
  float* out          = (float*)d_out;
  const int B = in_sizes[0] / 3;

  // Replicate numpy's double-precision resolution computation bit-exactly.
  LevelParams lp;
  const double factor = exp((log(512.0) - log(16.0)) / 15.0);
  for (int i = 0; i < kLevels; ++i) {
    const int res = (int)floor(16.0 * pow(factor, (double)i));
    lp.scale[i] = (float)res * 0.5f;
    lp.resm1[i] = (float)(res - 1);
  }

  const int block = 256;
  const int grid = (B + block - 1) / block;
  const size_t ws_needed = (size_t)B * 2 * kLevels * sizeof(float);

  if (ws_size >= ws_needed) {
    float* out_t = (float*)d_ws;
    // levels 0..6 fused: combined table footprint ~4.3 MB (L2-friendly)
    hipLaunchKernelGGL((level_kernel<0, 7>), dim3(grid), dim3(block), 0, stream,
                       x, tables, out_t, lp, B);
    // levels 7..15: one dispatch per level => chip-wide single-table phase,
    // 4 MB table resident per XCD L2.
    hipLaunchKernelGGL((level_kernel<7, 8>),  dim3(grid), dim3(block), 0, stream, x, tables, out_t, lp, B);
    hipLaunchKernelGGL((level_kernel<8, 9>),  dim3(grid), dim3(block), 0, stream, x, tables, out_t, lp, B);
    hipLaunchKernelGGL((level_kernel<9, 10>), dim3(grid), dim3(block), 0, stream, x, tables, out_t, lp, B);
    hipLaunchKernelGGL((level_kernel<10, 11>), dim3(grid), dim3(block), 0, stream, x, tables, out_t, lp, B);
    hipLaunchKernelGGL((level_kernel<11, 12>), dim3(grid), dim3(block), 0, stream, x, tables, out_t, lp, B);
    hipLaunchKernelGGL((level_kernel<12, 13>), dim3(grid), dim3(block), 0, stream, x, tables, out_t, lp, B);
    hipLaunchKernelGGL((level_kernel<13, 14>), dim3(grid), dim3(block), 0, stream, x, tables, out_t, lp, B);
    hipLaunchKernelGGL((level_kernel<14, 15>), dim3(grid), dim3(block), 0, stream, x, tables, out_t, lp, B);
    hipLaunchKernelGGL((level_kernel<15, 16>), dim3(grid), dim3(block), 0, stream, x, tables, out_t, lp, B);
    // assemble rows: register transpose, fully coalesced both sides
    hipLaunchKernelGGL(transpose_kernel, dim3(grid), dim3(block), 0, stream,
                       out_t, out, B);
  } else {
    hipLaunchKernelGGL(monolith_kernel, dim3(grid), dim3(block), 0, stream,
                       x, tables, out, lp, B);
  }
}

// Round 4
// 752.415 us; speedup vs baseline: 1.6493x; 1.0126x over previous
//
#include <hip/hip_runtime.h>
#include <cmath>

constexpr int kLevels = 16;
constexpr unsigned kLog2T = 19;
constexpr unsigned kT = 1u << kLog2T;
constexpr unsigned kMask = kT - 1u;
constexpr unsigned P1 = 2654435761u;
constexpr unsigned P2 = 805459861u;

struct LevelParams {
  float scale[kLevels];   // res * 0.5  (u = (x+1) * res/2)
  float resm1[kLevels];   // res - 1    (clip bound for floor(u))
};

// Bijective XCD swizzle (8 XCDs, round-robin dispatch): block b -> chunk
// (b&7)*C + (b>>3). Every kernel uses the same point->XCD mapping (each XCD
// owns one contiguous eighth of the point range), so per-dispatch x reads
// fill only 12 MB of L2 total instead of 12 MB x 8 XCDs.
__device__ __forceinline__ int swz_block(int bid, int nblk) {
  const int C = nblk >> 3;
  return (bid & 7) * C + (bid >> 3);
}

// ---------------------------------------------------------------------------
// Per-level(s) kernel, 2 points per thread. Writes TRANSPOSED scratch
// out_t[l][p][2]; the 2 points are contiguous -> one float4 store per level.
// Chip-wide level phase is enforced by stream-ordered per-level dispatches:
// the active 4 MB table stays resident in each XCD's 4 MB L2.
// ---------------------------------------------------------------------------
template <int LO, int HI>
__global__ __launch_bounds__(256) void level_kernel(
    const float* __restrict__ x,
    const float* __restrict__ tables,
    float* __restrict__ out_t,   // [kLevels][B][2]
    LevelParams lp, int B)
{
  const int eb  = swz_block(blockIdx.x, gridDim.x);
  const int idx = eb * 512 + (int)threadIdx.x * 2;   // first of 2 points
  if (idx >= B) return;

  // 6 contiguous floats (2 points x 3 coords), 8B-aligned
  const float2* __restrict__ xv = (const float2*)(x + (size_t)3 * idx);
  const float2 xa = xv[0];
  const float2 xb = xv[1];
  const float2 xc = xv[2];
  const float px[2] = {xa.x, xb.y};
  const float py[2] = {xa.y, xc.x};
  const float pz[2] = {xb.x, xc.y};

#pragma unroll
  for (int l = LO; l < HI; ++l) {
    const float s   = lp.scale[l];
    const float rm1 = lp.resm1[l];
    const float2* __restrict__ tbl = (const float2*)tables + (size_t)l * kT;

    unsigned h[2][8];
    float w[2][8];

#pragma unroll
    for (int q = 0; q < 2; ++q) {
      const float ux = (px[q] + 1.0f) * s;
      const float uy = (py[q] + 1.0f) * s;
      const float uz = (pz[q] + 1.0f) * s;

      const float fx = fminf(fmaxf(floorf(ux), 0.0f), rm1);
      const float fy = fminf(fmaxf(floorf(uy), 0.0f), rm1);
      const float fz = fminf(fmaxf(floorf(uz), 0.0f), rm1);

      const float tx = ux - fx;
      const float ty = uy - fy;
      const float tz = uz - fz;

      const unsigned ix = (unsigned)fx;
      const unsigned iy = (unsigned)fy;
      const unsigned iz = (unsigned)fz;

      // h = (ix+ox) ^ (iy+oy)*P1 ^ (iz+oz)*P2 (uint32 wraparound), 2 mults.
      const unsigned ax0 = ix, ax1 = ix + 1u;
      const unsigned by0 = iy * P1, by1 = by0 + P1;
      const unsigned cz0 = iz * P2, cz1 = cz0 + P2;

      const unsigned bc00 = by0 ^ cz0;
      const unsigned bc10 = by1 ^ cz0;
      const unsigned bc01 = by0 ^ cz1;
      const unsigned bc11 = by1 ^ cz1;

      h[q][0] = (ax0 ^ bc00) & kMask;
      h[q][1] = (ax1 ^ bc00) & kMask;
      h[q][2] = (ax0 ^ bc10) & kMask;
      h[q][3] = (ax1 ^ bc10) & kMask;
      h[q][4] = (ax0 ^ bc01) & kMask;
      h[q][5] = (ax1 ^ bc01) & kMask;
      h[q][6] = (ax0 ^ bc11) & kMask;
      h[q][7] = (ax1 ^ bc11) & kMask;

      const float wx1 = tx, wx0 = 1.0f - tx;
      const float wy1 = ty, wy0 = 1.0f - ty;
      const float wz1 = tz, wz0 = 1.0f - tz;

      const float wyz00 = wy0 * wz0;
      const float wyz10 = wy1 * wz0;
      const float wyz01 = wy0 * wz1;
      const float wyz11 = wy1 * wz1;

      w[q][0] = wx0 * wyz00;  w[q][1] = wx1 * wyz00;
      w[q][2] = wx0 * wyz10;  w[q][3] = wx1 * wyz10;
      w[q][4] = wx0 * wyz01;  w[q][5] = wx1 * wyz01;
      w[q][6] = wx0 * wyz11;  w[q][7] = wx1 * wyz11;
    }

    // issue all 16 gathers back-to-back (max MLP), then consume
    float2 e[2][8];
#pragma unroll
    for (int q = 0; q < 2; ++q)
#pragma unroll
      for (int c = 0; c < 8; ++c)
        e[q][c] = tbl[h[q][c]];

    float4 r;
    {
      float f0 = w[0][0] * e[0][0].x;
      float f1 = w[0][0] * e[0][0].y;
#pragma unroll
      for (int c = 1; c < 8; ++c) {
        f0 = fmaf(w[0][c], e[0][c].x, f0);
        f1 = fmaf(w[0][c], e[0][c].y, f1);
      }
      float g0 = w[1][0] * e[1][0].x;
      float g1 = w[1][0] * e[1][0].y;
#pragma unroll
      for (int c = 1; c < 8; ++c) {
        g0 = fmaf(w[1][c], e[1][c].x, g0);
        g1 = fmaf(w[1][c], e[1][c].y, g1);
      }
      r = make_float4(f0, f1, g0, g1);
    }

    // 2 contiguous points -> one 16B full-coalesced store into level slice
    *(float4*)(out_t + (size_t)l * 2 * B + (size_t)2 * idx) = r;
  }
}

// ---------------------------------------------------------------------------
// Register transpose, 2 points/thread: per level one float4 load (coalesced,
// same-XCD L2/L3 slice thanks to the shared swizzle), then two 128B rows
// written as 8x float4 each.
// ---------------------------------------------------------------------------
__global__ __launch_bounds__(256) void transpose_kernel(
    const float* __restrict__ out_t, float* __restrict__ out, int B)
{
  const int eb  = swz_block(blockIdx.x, gridDim.x);
  const int idx = eb * 512 + (int)threadIdx.x * 2;
  if (idx >= B) return;

  float r0[2 * kLevels];
  float r1[2 * kLevels];
#pragma unroll
  for (int l = 0; l < kLevels; ++l) {
    const float4 v = *(const float4*)(out_t + (size_t)l * 2 * B + (size_t)2 * idx);
    r0[2 * l + 0] = v.x;  r0[2 * l + 1] = v.y;
    r1[2 * l + 0] = v.z;  r1[2 * l + 1] = v.w;
  }
  float4* __restrict__ row0 = (float4*)(out + (size_t)idx * (2 * kLevels));
  float4* __restrict__ row1 = (float4*)(out + (size_t)(idx + 1) * (2 * kLevels));
#pragma unroll
  for (int q = 0; q < 8; ++q)
    row0[q] = make_float4(r0[4 * q], r0[4 * q + 1], r0[4 * q + 2], r0[4 * q + 3]);
#pragma unroll
  for (int q = 0; q < 8; ++q)
    row1[q] = make_float4(r1[4 * q], r1[4 * q + 1], r1[4 * q + 2], r1[4 * q + 3]);
}

// ---------------------------------------------------------------------------
// Fallback monolith (round-1 kernel, known-correct) if workspace too small.
// ---------------------------------------------------------------------------
__global__ __launch_bounds__(256) void monolith_kernel(
    const float* __restrict__ x,
    const float* __restrict__ tables,
    float* __restrict__ out,
    LevelParams lp, int B)
{
  const int b = blockIdx.x * 256 + threadIdx.x;
  if (b >= B) return;

  const float px = x[3 * b + 0];
  const float py = x[3 * b + 1];
  const float pz = x[3 * b + 2];
  float* orow = out + (size_t)b * (2 * kLevels);

  const float2* tbl = (const float2*)tables;
  for (int l = 0; l < kLevels; ++l, tbl += kT) {
    const float s   = lp.scale[l];
    const float rm1 = lp.resm1[l];

    const float ux = (px + 1.0f) * s;
    const float uy = (py + 1.0f) * s;
    const float uz = (pz + 1.0f) * s;

    const float fx = fminf(fmaxf(floorf(ux), 0.0f), rm1);
    const float fy = fminf(fmaxf(floorf(uy), 0.0f), rm1);
    const float fz = fminf(fmaxf(floorf(uz), 0.0f), rm1);

    const float tx = ux - fx;
    const float ty = uy - fy;
    const float tz = uz - fz;

    const unsigned ix = (unsigned)fx;
    const unsigned iy = (unsigned)fy;
    const unsigned iz = (unsigned)fz;

    const unsigned ax0 = ix, ax1 = ix + 1u;
    const unsigned by0 = iy * P1, by1 = by0 + P1;
    const unsigned cz0 = iz * P2, cz1 = cz0 + P2;

    const unsigned bc00 = by0 ^ cz0;
    const unsigned bc10 = by1 ^ cz0;
    const unsigned bc01 = by0 ^ cz1;
    const unsigned bc11 = by1 ^ cz1;

    const float2 e000 = tbl[(ax0 ^ bc00) & kMask];
    const float2 e100 = tbl[(ax1 ^ bc00) & kMask];
    const float2 e010 = tbl[(ax0 ^ bc10) & kMask];
    const float2 e110 = tbl[(ax1 ^ bc10) & kMask];
    const float2 e001 = tbl[(ax0 ^ bc01) & kMask];
    const float2 e101 = tbl[(ax1 ^ bc01) & kMask];
    const float2 e011 = tbl[(ax0 ^ bc11) & kMask];
    const float2 e111 = tbl[(ax1 ^ bc11) & kMask];

    const float wx1 = tx, wx0 = 1.0f - tx;
    const float wy1 = ty, wy0 = 1.0f - ty;
    const float wz1 = tz, wz0 = 1.0f - tz;

    const float wyz00 = wy0 * wz0;
    const float wyz10 = wy1 * wz0;
    const float wyz01 = wy0 * wz1;
    const float wyz11 = wy1 * wz1;

    const float w000 = wx0 * wyz00, w100 = wx1 * wyz00;
    const float w010 = wx0 * wyz10, w110 = wx1 * wyz10;
    const float w001 = wx0 * wyz01, w101 = wx1 * wyz01;
    const float w011 = wx0 * wyz11, w111 = wx1 * wyz11;

    float f0 = w000 * e000.x;
    float f1 = w000 * e000.y;
    f0 = fmaf(w100, e100.x, f0);  f1 = fmaf(w100, e100.y, f1);
    f0 = fmaf(w010, e010.x, f0);  f1 = fmaf(w010, e010.y, f1);
    f0 = fmaf(w110, e110.x, f0);  f1 = fmaf(w110, e110.y, f1);
    f0 = fmaf(w001, e001.x, f0);  f1 = fmaf(w001, e001.y, f1);
    f0 = fmaf(w101, e101.x, f0);  f1 = fmaf(w101, e101.y, f1);
    f0 = fmaf(w011, e011.x, f0);  f1 = fmaf(w011, e011.y, f1);
    f0 = fmaf(w111, e111.x, f0);  f1 = fmaf(w111, e111.y, f1);

    orow[2 * l + 0] = f0;
    orow[2 * l + 1] = f1;
  }
}

extern "C" void kernel_launch(void* const* d_in, const int* in_sizes, int n_in,
                              void* d_out, int out_size, void* d_ws, size_t ws_size,
                              hipStream_t stream) {
  const float* x      = (const float*)d_in[0];
  const float* tables = (const float*)d_in[1];
  float* out          = (float*)d_out;
  const int B = in_sizes[0] / 3;

  // Replicate numpy's double-precision resolution computation bit-exactly.
  LevelParams lp;
  const double factor = exp((log(512.0) - log(16.0)) / 15.0);
  for (int i = 0; i < kLevels; ++i) {
    const int res = (int)floor(16.0 * pow(factor, (double)i));
    lp.scale[i] = (float)res * 0.5f;
    lp.resm1[i] = (float)(res - 1);
  }

  const int block = 256;
  const size_t ws_needed = (size_t)B * 2 * kLevels * sizeof(float);

  // grids: multiples of 8 for the bijective XCD swizzle
  const int grid2 = (((B + 511) / 512 + 7) / 8) * 8;    // 2 points/thread
  const size_t gsz = (size_t)grid2;
  (void)gsz;

  if (ws_size >= ws_needed && (B % 2) == 0) {
    float* out_t = (float*)d_ws;
    // levels 0..6 fused: combined table footprint ~3.3 MB (L2-friendly)
    hipLaunchKernelGGL((level_kernel<0, 7>), dim3(grid2), dim3(block), 0, stream,
                       x, tables, out_t, lp, B);
    // levels 7..15: one dispatch per level => chip-wide single-table phase
    hipLaunchKernelGGL((level_kernel<7, 8>),   dim3(grid2), dim3(block), 0, stream, x, tables, out_t, lp, B);
    hipLaunchKernelGGL((level_kernel<8, 9>),   dim3(grid2), dim3(block), 0, stream, x, tables, out_t, lp, B);
    hipLaunchKernelGGL((level_kernel<9, 10>),  dim3(grid2), dim3(block), 0, stream, x, tables, out_t, lp, B);
    hipLaunchKernelGGL((level_kernel<10, 11>), dim3(grid2), dim3(block), 0, stream, x, tables, out_t, lp, B);
    hipLaunchKernelGGL((level_kernel<11, 12>), dim3(grid2), dim3(block), 0, stream, x, tables, out_t, lp, B);
    hipLaunchKernelGGL((level_kernel<12, 13>), dim3(grid2), dim3(block), 0, stream, x, tables, out_t, lp, B);
    hipLaunchKernelGGL((level_kernel<13, 14>), dim3(grid2), dim3(block), 0, stream, x, tables, out_t, lp, B);
    hipLaunchKernelGGL((level_kernel<14, 15>), dim3(grid2), dim3(block), 0, stream, x, tables, out_t, lp, B);
    hipLaunchKernelGGL((level_kernel<15, 16>), dim3(grid2), dim3(block), 0, stream, x, tables, out_t, lp, B);
    // assemble rows
    hipLaunchKernelGGL(transpose_kernel, dim3(grid2), dim3(block), 0, stream,
                       out_t, out, B);
  } else {
    const int grid = (B + block - 1) / block;
    hipLaunchKernelGGL(monolith_kernel, dim3(grid), dim3(block), 0, stream,
                       x, tables, out, lp, B);
  }
}